// Round 1
// baseline (347.713 us; speedup 1.0000x reference)
//
#include <hip/hip_runtime.h>

#define NGATES 78
#define LEAKY(x) ((x) > 0.0f ? (x) : 0.01f * (x))

struct GateRec { int kind, a, b, pad; float m[8]; }; // 48 B

__device__ __forceinline__ float2 cmul(float2 a, float2 b) {
  return make_float2(a.x*b.x - a.y*b.y, a.x*b.y + a.y*b.x);
}
__device__ __forceinline__ float2 cadd(float2 a, float2 b) {
  return make_float2(a.x + b.x, a.y + b.y);
}

struct C2 { float2 e[4]; }; // row-major 2x2 complex

__device__ C2 cmm(const C2& A, const C2& B) {
  C2 R;
  #pragma unroll
  for (int r = 0; r < 2; ++r)
    #pragma unroll
    for (int c = 0; c < 2; ++c)
      R.e[r*2+c] = cadd(cmul(A.e[r*2+0], B.e[0*2+c]), cmul(A.e[r*2+1], B.e[1*2+c]));
  return R;
}
__device__ C2 gRX(float t) {
  float s, c; sincosf(0.5f*t, &s, &c);
  C2 M;
  M.e[0] = make_float2(c, 0.f);  M.e[1] = make_float2(0.f, -s);
  M.e[2] = make_float2(0.f, -s); M.e[3] = make_float2(c, 0.f);
  return M;
}
__device__ C2 gRY(float t) {
  float s, c; sincosf(0.5f*t, &s, &c);
  C2 M;
  M.e[0] = make_float2(c, 0.f);  M.e[1] = make_float2(-s, 0.f);
  M.e[2] = make_float2(s, 0.f);  M.e[3] = make_float2(c, 0.f);
  return M;
}
__device__ C2 gRZ(float t) {
  float s, c; sincosf(0.5f*t, &s, &c);
  C2 M;
  M.e[0] = make_float2(c, -s); M.e[1] = make_float2(0.f, 0.f);
  M.e[2] = make_float2(0.f, 0.f); M.e[3] = make_float2(c, s);
  return M;
}
__device__ C2 gROT(float phi, float th, float om) {
  return cmm(cmm(gRZ(om), gRY(th)), gRZ(phi));
}

// Builds the 78 UE-independent gate matrices. Wire w <-> bit position (8-w).
__global__ void setup_gates(const float* __restrict__ strongp,
                            const float* __restrict__ initsp,
                            const float* __restrict__ updatep,
                            GateRec* __restrict__ gates) {
  if (threadIdx.x != 0 || blockIdx.x != 0) return;
  int g = 0;
  auto emitU = [&](int kind, int a, int b, C2 U) {
    GateRec r; r.kind = kind; r.a = a; r.b = b; r.pad = 0;
    r.m[0]=U.e[0].x; r.m[1]=U.e[0].y; r.m[2]=U.e[1].x; r.m[3]=U.e[1].y;
    r.m[4]=U.e[2].x; r.m[5]=U.e[2].y; r.m[6]=U.e[3].x; r.m[7]=U.e[3].y;
    gates[g++] = r;
  };
  auto emitCX = [&](int c, int t) {
    GateRec r; r.kind = 2; r.a = c; r.b = t; r.pad = 0;
    #pragma unroll
    for (int k = 0; k < 8; ++k) r.m[k] = 0.f;
    gates[g++] = r;
  };
  // edge blocks: e=i, nb=4+i
  for (int i = 0; i < 3; ++i) {
    int e = i, nb = 4 + i;
    emitU(1, nb, e, gRX(initsp[0]));   // apc(RX(inits[0,0]), c=nb, t=e)
    emitU(1, e, nb, gRY(initsp[1]));   // apc(RY(inits[0,1]), c=e, t=nb)
    for (int l = 0; l < 2; ++l) {      // sel(strong[0], [e, nb]), r = 1
      emitU(0, e,  0, gROT(strongp[l*6+0], strongp[l*6+1], strongp[l*6+2]));
      emitU(0, nb, 0, gROT(strongp[l*6+3], strongp[l*6+4], strongp[l*6+5]));
      emitCX(e, nb);
      emitCX(nb, e);
    }
  }
  // update blocks: wires {3, 4+i, 7, 8}
  for (int i = 0; i < 3; ++i) {
    int W[4] = {3, 4 + i, 7, 8};
    for (int l = 0; l < 2; ++l) {
      for (int j = 0; j < 4; ++j) {
        const float* p = updatep + i*24 + l*12 + j*3;
        emitU(0, W[j], 0, gROT(p[0], p[1], p[2]));
      }
      int r = l % 3 + 1;
      for (int j = 0; j < 4; ++j) emitCX(W[j], W[(j + r) & 3]);
    }
  }
}

// generic 2-layer MLP encoder: out[r,0:2] = leaky(x[r]@W1+b1)@W2+b2
__global__ void mlp_encode(const float* __restrict__ x, int n, int d,
                           const float* __restrict__ W1, const float* __restrict__ b1,
                           const float* __restrict__ W2, const float* __restrict__ b2,
                           float* __restrict__ out) {
  int r = blockIdx.x * blockDim.x + threadIdx.x;
  if (r >= n) return;
  float xi[8];
  for (int k = 0; k < d; ++k) xi[k] = x[r*d + k];
  float o0 = 0.f, o1 = 0.f;
  for (int j = 0; j < 128; ++j) {
    float h = b1[j];
    for (int k = 0; k < d; ++k) h = fmaf(xi[k], W1[k*128 + j], h);
    h = LEAKY(h);
    o0 = fmaf(h, W2[j*2 + 0], o0);
    o1 = fmaf(h, W2[j*2 + 1], o1);
  }
  out[r*2 + 0] = o0 + b2[0];
  out[r*2 + 1] = o1 + b2[1];
}

// One wave per UE; 2 UEs per 128-thread block. 512-amp state in LDS.
__global__ __launch_bounds__(128) void circuit_kernel(
    const float* __restrict__ ue, const float* __restrict__ apf,
    const float* __restrict__ ea, const int* __restrict__ esrc,
    const GateRec* __restrict__ gates,
    const float* __restrict__ Wu1, const float* __restrict__ bu1,
    const float* __restrict__ Wu2, const float* __restrict__ bu2,
    const float* __restrict__ lng, const float* __restrict__ lnb,
    const float* __restrict__ Wf1, const float* __restrict__ bf1,
    const float* __restrict__ Wf2, const float* __restrict__ bf2,
    const float* __restrict__ Wf3, const float* __restrict__ bf3,
    float* __restrict__ out) {
  __shared__ float2 psi_s[2][512];
  __shared__ float act_s[2][128];
  const int wv = threadIdx.x >> 6;
  const int lane = threadIdx.x & 63;
  const int u = blockIdx.x * 2 + wv;
  float2* psi = psi_s[wv];
  float* act = act_s[wv];

  // --- product-state init: psi = prod_w (RZ(b_w) RX(a_w) |0>), wires 7,8 = |0>
  const float ue0 = ue[u*2 + 0], ue1 = ue[u*2 + 1];
  float2 v0[7], v1[7];
  #pragma unroll
  for (int w = 0; w < 7; ++w) {
    float aa, bb;
    if (w < 3)       { aa = ea[(u*3 + w)*2 + 0]; bb = ea[(u*3 + w)*2 + 1]; }
    else if (w == 3) { aa = ue0; bb = ue1; }
    else             { int s = esrc[u*3 + (w - 4)]; aa = apf[s*2 + 0]; bb = apf[s*2 + 1]; }
    float sa, ca, sb, cb;
    sincosf(0.5f*aa, &sa, &ca);
    sincosf(0.5f*bb, &sb, &cb);
    v0[w] = make_float2(cb*ca, -sb*ca);          // e^{-ib/2} cos(a/2)
    v1[w] = make_float2(sa*sb, -sa*cb);          // e^{+ib/2} (-i sin(a/2))
  }
  #pragma unroll
  for (int k = 0; k < 8; ++k) {
    int idx = k*64 + lane;
    float2 amp;
    if (idx & 3) amp = make_float2(0.f, 0.f);    // wires 7/8 (bits 1/0) must be 0
    else {
      amp = make_float2(1.f, 0.f);
      #pragma unroll
      for (int w = 0; w < 7; ++w)
        amp = cmul(amp, ((idx >> (8 - w)) & 1) ? v1[w] : v0[w]);
    }
    psi[idx] = amp;
  }
  __syncthreads();

  // --- apply the 78 shared gates
  for (int g = 0; g < NGATES; ++g) {
    GateRec gr = gates[g];
    if (gr.kind == 0) {                           // single-qubit U on wire gr.a
      const int m = 1 << (8 - gr.a);
      const float2 u00 = make_float2(gr.m[0], gr.m[1]);
      const float2 u01 = make_float2(gr.m[2], gr.m[3]);
      const float2 u10 = make_float2(gr.m[4], gr.m[5]);
      const float2 u11 = make_float2(gr.m[6], gr.m[7]);
      #pragma unroll
      for (int p = 0; p < 4; ++p) {
        int j = p*64 + lane;                      // 256 pairs
        int i0 = ((j & ~(m - 1)) << 1) | (j & (m - 1));
        int i1 = i0 | m;
        float2 a0 = psi[i0], a1 = psi[i1];
        psi[i0] = cadd(cmul(u00, a0), cmul(u01, a1));
        psi[i1] = cadd(cmul(u10, a0), cmul(u11, a1));
      }
    } else {                                      // controlled (c=gr.a, t=gr.b)
      const int mc = 1 << (8 - gr.a);
      const int mt = 1 << (8 - gr.b);
      const int lo = mc < mt ? mc : mt;
      const int hi = mc < mt ? mt : mc;
      const float2 u00 = make_float2(gr.m[0], gr.m[1]);
      const float2 u01 = make_float2(gr.m[2], gr.m[3]);
      const float2 u10 = make_float2(gr.m[4], gr.m[5]);
      const float2 u11 = make_float2(gr.m[6], gr.m[7]);
      const bool isCX = (gr.kind == 2);
      #pragma unroll
      for (int p = 0; p < 2; ++p) {
        int j = p*64 + lane;                      // 128 pairs (control = 1)
        int x = ((j & ~(lo - 1)) << 1) | (j & (lo - 1));
        x = ((x & ~(hi - 1)) << 1) | (x & (hi - 1));
        int i0 = x | mc;                          // c=1, t=0
        int i1 = x | mc | mt;                     // c=1, t=1
        float2 a0 = psi[i0], a1 = psi[i1];
        if (isCX) { psi[i0] = a1; psi[i1] = a0; }
        else {
          psi[i0] = cadd(cmul(u00, a0), cmul(u01, a1));
          psi[i1] = cadd(cmul(u10, a0), cmul(u11, a1));
        }
      }
    }
    __syncthreads();
  }

  // --- expz on wires 3 (bit 5), 7 (bit 1), 8 (bit 0)
  float s3 = 0.f, s7 = 0.f, s8 = 0.f;
  #pragma unroll
  for (int k = 0; k < 8; ++k) {
    int idx = k*64 + lane;
    float2 a = psi[idx];
    float p = a.x*a.x + a.y*a.y;
    s3 += ((idx >> 5) & 1) ? -p : p;
    s7 += ((idx >> 1) & 1) ? -p : p;
    s8 += (idx & 1) ? -p : p;
  }
  #pragma unroll
  for (int o = 32; o; o >>= 1) {
    s3 += __shfl_xor(s3, o);
    s7 += __shfl_xor(s7, o);
    s8 += __shfl_xor(s8, o);
  }

  // --- upd = mlp2([ue, msg], Wu1, bu1, Wu2, bu2); h = ue + upd
  const int j1 = lane, j2 = lane + 64;
  float in5[5] = {ue0, ue1, s3, s7, s8};
  float h1 = bu1[j1], h2 = bu1[j2];
  #pragma unroll
  for (int k = 0; k < 5; ++k) {
    h1 = fmaf(in5[k], Wu1[k*128 + j1], h1);
    h2 = fmaf(in5[k], Wu1[k*128 + j2], h2);
  }
  h1 = LEAKY(h1); h2 = LEAKY(h2);
  float p0 = h1*Wu2[j1*2 + 0] + h2*Wu2[j2*2 + 0];
  float p1 = h1*Wu2[j1*2 + 1] + h2*Wu2[j2*2 + 1];
  #pragma unroll
  for (int o = 32; o; o >>= 1) { p0 += __shfl_xor(p0, o); p1 += __shfl_xor(p1, o); }
  float hh0 = ue0 + p0 + bu2[0];
  float hh1 = ue1 + p1 + bu2[1];

  // --- layernorm over 2 elems: var = ((h0-h1)/2)^2
  float mu = 0.5f*(hh0 + hh1);
  float dd = hh0 - mu;
  float inv = rsqrtf(dd*dd + 1e-5f);
  float g0 = dd*inv*lng[0] + lnb[0];
  float g1 = -dd*inv*lng[1] + lnb[1];

  // --- head: 2->128 (leaky) ->128 (leaky) ->2 (sigmoid)
  float a1f = LEAKY(g0*Wf1[j1]       + g1*Wf1[128 + j1] + bf1[j1]);
  float a2f = LEAKY(g0*Wf1[j2]       + g1*Wf1[128 + j2] + bf1[j2]);
  act[j1] = a1f; act[j2] = a2f;
  __syncthreads();
  float c1 = bf2[j1], c2 = bf2[j2];
  for (int k = 0; k < 128; ++k) {
    float ak = act[k];
    c1 = fmaf(ak, Wf2[k*128 + j1], c1);
    c2 = fmaf(ak, Wf2[k*128 + j2], c2);
  }
  c1 = LEAKY(c1); c2 = LEAKY(c2);
  float o0 = c1*Wf3[j1*2 + 0] + c2*Wf3[j2*2 + 0];
  float o1 = c1*Wf3[j1*2 + 1] + c2*Wf3[j2*2 + 1];
  #pragma unroll
  for (int o = 32; o; o >>= 1) { o0 += __shfl_xor(o0, o); o1 += __shfl_xor(o1, o); }
  if (lane == 0) {
    out[u*2 + 0] = 1.f/(1.f + expf(-(o0 + bf3[0])));
    out[u*2 + 1] = 1.f/(1.f + expf(-(o1 + bf3[1])));
  }
}

extern "C" void kernel_launch(void* const* d_in, const int* in_sizes, int n_in,
                              void* d_out, int out_size, void* d_ws, size_t ws_size,
                              hipStream_t stream) {
  (void)in_sizes; (void)n_in; (void)out_size; (void)ws_size;
  const float* x_ue      = (const float*)d_in[0];
  const float* x_ap      = (const float*)d_in[1];
  const float* edge_attr = (const float*)d_in[2];
  const int*   edge_src  = (const int*)d_in[3];
  // d_in[4] = edge_dst (unused)
  const float* Wn1u = (const float*)d_in[5];
  const float* bn1u = (const float*)d_in[6];
  const float* Wn2u = (const float*)d_in[7];
  const float* bn2u = (const float*)d_in[8];
  const float* Wn1a = (const float*)d_in[9];
  const float* bn1a = (const float*)d_in[10];
  const float* Wn2a = (const float*)d_in[11];
  const float* bn2a = (const float*)d_in[12];
  const float* We1  = (const float*)d_in[13];
  const float* be1  = (const float*)d_in[14];
  const float* We2  = (const float*)d_in[15];
  const float* be2  = (const float*)d_in[16];
  const float* strong = (const float*)d_in[17];
  const float* inits  = (const float*)d_in[18];
  const float* update = (const float*)d_in[19];
  const float* Wu1  = (const float*)d_in[20];
  const float* bu1  = (const float*)d_in[21];
  const float* Wu2  = (const float*)d_in[22];
  const float* bu2  = (const float*)d_in[23];
  const float* ln_g = (const float*)d_in[24];
  const float* ln_b = (const float*)d_in[25];
  const float* Wf1  = (const float*)d_in[26];
  const float* bf1  = (const float*)d_in[27];
  const float* Wf2  = (const float*)d_in[28];
  const float* bf2  = (const float*)d_in[29];
  const float* Wf3  = (const float*)d_in[30];
  const float* bf3  = (const float*)d_in[31];

  float* ws = (float*)d_ws;
  float* ue = ws;                 // 8192*2
  float* ap = ue + 16384;         // 2048*2
  float* ea = ap + 4096;          // 24576*2
  GateRec* gates = (GateRec*)(ea + 49152);

  mlp_encode<<<(8192  + 255)/256, 256, 0, stream>>>(x_ue,      8192,  8, Wn1u, bn1u, Wn2u, bn2u, ue);
  mlp_encode<<<(2048  + 255)/256, 256, 0, stream>>>(x_ap,      2048,  8, Wn1a, bn1a, Wn2a, bn2a, ap);
  mlp_encode<<<(24576 + 255)/256, 256, 0, stream>>>(edge_attr, 24576, 4, We1,  be1,  We2,  be2,  ea);
  setup_gates<<<1, 64, 0, stream>>>(strong, inits, update, gates);
  circuit_kernel<<<4096, 128, 0, stream>>>(ue, ap, ea, edge_src, gates,
                                           Wu1, bu1, Wu2, bu2, ln_g, ln_b,
                                           Wf1, bf1, Wf2, bf2, Wf3, bf3,
                                           (float*)d_out);
}

// Round 2
// 62.217 us; speedup vs baseline: 5.5887x; 5.5887x over previous
//
#include <hip/hip_runtime.h>

#define LEAKY(x) ((x) > 0.0f ? (x) : 0.01f * (x))

// ws float layout
#define UE_OFF 0
#define AP_OFF 16384
#define EA_OFF (16384 + 4096)
#define ME_OFF (EA_OFF + 49152)   // 32 floats: M_edge 4x4 complex
#define ROT_OFF (ME_OFF + 32)     // 192 floats: 24 ROT 2x2 complex matrices

__device__ __forceinline__ float2 cmul(float2 a, float2 b) {
  return make_float2(fmaf(a.x, b.x, -a.y * b.y), fmaf(a.x, b.y, a.y * b.x));
}
__device__ __forceinline__ float2 cadd(float2 a, float2 b) {
  return make_float2(a.x + b.x, a.y + b.y);
}
__device__ __forceinline__ float2 shflx(float2 v, int m) {
  return make_float2(__shfl_xor(v.x, m), __shfl_xor(v.y, m));
}
__device__ __forceinline__ void cswap(bool c, float2& a, float2& b) {
  float2 na = c ? b : a, nb = c ? a : b;
  a = na; b = nb;
}
__device__ __forceinline__ void swap2(float2& a, float2& b) {
  float2 t = a; a = b; b = t;
}

struct C2 { float2 e[4]; }; // row-major 2x2 complex

__device__ C2 cmm(const C2& A, const C2& B) {
  C2 R;
  #pragma unroll
  for (int r = 0; r < 2; ++r)
    #pragma unroll
    for (int c = 0; c < 2; ++c)
      R.e[r*2+c] = cadd(cmul(A.e[r*2+0], B.e[0*2+c]), cmul(A.e[r*2+1], B.e[1*2+c]));
  return R;
}
__device__ C2 gRX(float t) {
  float s, c; sincosf(0.5f*t, &s, &c);
  C2 M;
  M.e[0] = make_float2(c, 0.f);  M.e[1] = make_float2(0.f, -s);
  M.e[2] = make_float2(0.f, -s); M.e[3] = make_float2(c, 0.f);
  return M;
}
__device__ C2 gRY(float t) {
  float s, c; sincosf(0.5f*t, &s, &c);
  C2 M;
  M.e[0] = make_float2(c, 0.f);  M.e[1] = make_float2(-s, 0.f);
  M.e[2] = make_float2(s, 0.f);  M.e[3] = make_float2(c, 0.f);
  return M;
}
__device__ C2 gRZ(float t) {
  float s, c; sincosf(0.5f*t, &s, &c);
  C2 M;
  M.e[0] = make_float2(c, -s);    M.e[1] = make_float2(0.f, 0.f);
  M.e[2] = make_float2(0.f, 0.f); M.e[3] = make_float2(c, s);
  return M;
}
__device__ C2 gROT(float phi, float th, float om) {
  return cmm(cmm(gRZ(om), gRY(th)), gRZ(phi));
}

// 2-layer MLP row encoder: out[r,0:2] = leaky(x[r]@W1+b1)@W2+b2
template<int D>
__device__ void enc_row(const float* __restrict__ x, int r,
                        const float* __restrict__ W1, const float* __restrict__ b1,
                        const float* __restrict__ W2, const float* __restrict__ b2,
                        float* __restrict__ out) {
  float xi[D];
  #pragma unroll
  for (int k = 0; k < D; ++k) xi[k] = x[r*D + k];
  float o0 = b2[0], o1 = b2[1];
  #pragma unroll 4
  for (int j = 0; j < 128; ++j) {
    float h = b1[j];
    #pragma unroll
    for (int k = 0; k < D; ++k) h = fmaf(xi[k], W1[k*128 + j], h);
    h = LEAKY(h);
    o0 = fmaf(h, W2[j*2 + 0], o0);
    o1 = fmaf(h, W2[j*2 + 1], o1);
  }
  out[r*2 + 0] = o0;
  out[r*2 + 1] = o1;
}

// Fused: 3 encoders + (one thread) gate-matrix precompute.
__global__ __launch_bounds__(256) void prep_kernel(
    const float* __restrict__ x_ue, const float* __restrict__ x_ap,
    const float* __restrict__ edge_attr,
    const float* __restrict__ Wn1u, const float* __restrict__ bn1u,
    const float* __restrict__ Wn2u, const float* __restrict__ bn2u,
    const float* __restrict__ Wn1a, const float* __restrict__ bn1a,
    const float* __restrict__ Wn2a, const float* __restrict__ bn2a,
    const float* __restrict__ We1,  const float* __restrict__ be1,
    const float* __restrict__ We2,  const float* __restrict__ be2,
    const float* __restrict__ strongp, const float* __restrict__ initsp,
    const float* __restrict__ updatep, float* __restrict__ ws) {
  int gid = blockIdx.x * blockDim.x + threadIdx.x;
  if (gid < 8192) {
    enc_row<8>(x_ue, gid, Wn1u, bn1u, Wn2u, bn2u, ws + UE_OFF);
  } else if (gid < 10240) {
    enc_row<8>(x_ap, gid - 8192, Wn1a, bn1a, Wn2a, bn2a, ws + AP_OFF);
  } else if (gid < 34816) {
    enc_row<4>(edge_attr, gid - 10240, We1, be1, We2, be2, ws + EA_OFF);
  } else if (gid == 34816) {
    // ---- M_edge: 4x4 unitary of one edge block, basis j = (b_e<<1)|b_nb
    float2 M[4][4];
    #pragma unroll
    for (int r = 0; r < 4; ++r)
      #pragma unroll
      for (int c = 0; c < 4; ++c)
        M[r][c] = make_float2(r == c ? 1.f : 0.f, 0.f);
    auto rowpair = [&](int r0, int r1, C2 U) {
      #pragma unroll
      for (int c = 0; c < 4; ++c) {
        float2 a0 = M[r0][c], a1 = M[r1][c];
        M[r0][c] = cadd(cmul(U.e[0], a0), cmul(U.e[1], a1));
        M[r1][c] = cadd(cmul(U.e[2], a0), cmul(U.e[3], a1));
      }
    };
    auto rowswap = [&](int r0, int r1) {
      #pragma unroll
      for (int c = 0; c < 4; ++c) { float2 t = M[r0][c]; M[r0][c] = M[r1][c]; M[r1][c] = t; }
    };
    rowpair(1, 3, gRX(initsp[0]));  // CRX: c=nb(bit0), t=e(bit1)
    rowpair(2, 3, gRY(initsp[1]));  // CRY: c=e(bit1), t=nb(bit0)
    #pragma unroll
    for (int l = 0; l < 2; ++l) {
      C2 Re = gROT(strongp[l*6+0], strongp[l*6+1], strongp[l*6+2]);
      C2 Rn = gROT(strongp[l*6+3], strongp[l*6+4], strongp[l*6+5]);
      rowpair(0, 2, Re); rowpair(1, 3, Re);   // ROT on e (bit1)
      rowpair(0, 1, Rn); rowpair(2, 3, Rn);   // ROT on nb (bit0)
      rowswap(2, 3);                           // CX(e -> nb)
      rowswap(1, 3);                           // CX(nb -> e)
    }
    float* mp = ws + ME_OFF;
    #pragma unroll
    for (int r = 0; r < 4; ++r)
      #pragma unroll
      for (int c = 0; c < 4; ++c) {
        mp[(r*4 + c)*2 + 0] = M[r][c].x;
        mp[(r*4 + c)*2 + 1] = M[r][c].y;
      }
    // ---- 24 update-block ROT matrices
    float* rp = ws + ROT_OFF;
    for (int i = 0; i < 3; ++i)
      for (int l = 0; l < 2; ++l)
        for (int j = 0; j < 4; ++j) {
          const float* p = updatep + i*24 + l*12 + j*3;
          C2 U = gROT(p[0], p[1], p[2]);
          float* q = rp + ((i*2 + l)*4 + j)*8;
          q[0]=U.e[0].x; q[1]=U.e[0].y; q[2]=U.e[1].x; q[3]=U.e[1].y;
          q[4]=U.e[2].x; q[5]=U.e[2].y; q[6]=U.e[3].x; q[7]=U.e[3].y;
        }
  }
}

// 2x2 on slot-bit pair mask MSK
template<int MSK>
__device__ __forceinline__ void rot_pairs(float2* amp, const float* __restrict__ rp) {
  float2 u00 = make_float2(rp[0], rp[1]), u01 = make_float2(rp[2], rp[3]);
  float2 u10 = make_float2(rp[4], rp[5]), u11 = make_float2(rp[6], rp[7]);
  #pragma unroll
  for (int s = 0; s < 8; ++s)
    if (!(s & MSK)) {
      float2 a0 = amp[s], a1 = amp[s | MSK];
      amp[s]       = cadd(cmul(u00, a0), cmul(u01, a1));
      amp[s | MSK] = cadd(cmul(u10, a0), cmul(u11, a1));
    }
}

// One wave per UE, state in registers: slot s = (b3<<2)|(b7<<1)|b8,
// lane = (b0<<5)|(b1<<4)|(b2<<3)|(b4<<2)|(b5<<1)|b6.
__global__ __launch_bounds__(128) void circuit_kernel(
    const float* __restrict__ ws, const int* __restrict__ esrc,
    const float* __restrict__ Wu1, const float* __restrict__ bu1,
    const float* __restrict__ Wu2, const float* __restrict__ bu2,
    const float* __restrict__ lng, const float* __restrict__ lnb,
    const float* __restrict__ Wf1, const float* __restrict__ bf1,
    const float* __restrict__ Wf2, const float* __restrict__ bf2,
    const float* __restrict__ Wf3, const float* __restrict__ bf3,
    float* __restrict__ out) {
  __shared__ float act_s[2][128];
  const int wv = threadIdx.x >> 6;
  const int lane = threadIdx.x & 63;
  const int u = blockIdx.x * 2 + wv;
  float* act = act_s[wv];
  const float* uep = ws + UE_OFF;
  const float* app = ws + AP_OFF;
  const float* eap = ws + EA_OFF;
  const float* mep = ws + ME_OFF;
  const float* rotc = ws + ROT_OFF;

  // ---- initial single-qubit states: v = RZ(b) RX(a) |0>
  const float ue0 = uep[u*2 + 0], ue1 = uep[u*2 + 1];
  float2 e0[3], e1[3], n0[3], n1[3], t0, t1;
  auto mkv = [](float aa, float bb, float2& v0, float2& v1) {
    float sa, ca, sb, cb;
    sincosf(0.5f*aa, &sa, &ca);
    sincosf(0.5f*bb, &sb, &cb);
    v0 = make_float2(cb*ca, -sb*ca);
    v1 = make_float2(sa*sb, -sa*cb);
  };
  #pragma unroll
  for (int i = 0; i < 3; ++i) {
    mkv(eap[(u*3 + i)*2 + 0], eap[(u*3 + i)*2 + 1], e0[i], e1[i]);
    int s = esrc[u*3 + i];
    mkv(app[s*2 + 0], app[s*2 + 1], n0[i], n1[i]);
  }
  mkv(ue0, ue1, t0, t1);

  // ---- edge phase: pair_i = M_edge @ (v_e ⊗ v_nb)
  float2 pr[3][4];
  #pragma unroll
  for (int i = 0; i < 3; ++i) {
    float2 in4[4] = {cmul(e0[i], n0[i]), cmul(e0[i], n1[i]),
                     cmul(e1[i], n0[i]), cmul(e1[i], n1[i])};
    #pragma unroll
    for (int r = 0; r < 4; ++r) {
      float2 acc = make_float2(0.f, 0.f);
      #pragma unroll
      for (int c = 0; c < 4; ++c) {
        float2 m = make_float2(mep[(r*4 + c)*2], mep[(r*4 + c)*2 + 1]);
        acc = cadd(acc, cmul(m, in4[c]));
      }
      pr[i][r] = acc;
    }
  }

  // ---- build register state
  float2 amp[8];
  {
    float2 P = make_float2(1.f, 0.f);
    #pragma unroll
    for (int i = 0; i < 3; ++i) {
      bool bE = (lane >> (5 - i)) & 1;
      bool bN = (lane >> (2 - i)) & 1;
      float2 lo = bN ? pr[i][1] : pr[i][0];
      float2 hi = bN ? pr[i][3] : pr[i][2];
      float2 si = bE ? hi : lo;
      P = cmul(P, si);
    }
    amp[0] = cmul(P, t0);
    amp[4] = cmul(P, t1);
    amp[1] = amp[2] = amp[3] = amp[5] = amp[6] = amp[7] = make_float2(0.f, 0.f);
  }

  // ---- update blocks: wires {3(slot bit2), 4+i(lane Lm), 7(bit1), 8(bit0)}
  #pragma unroll
  for (int i = 0; i < 3; ++i) {
    const int Lm = 4 >> i;
    const bool cb = (lane & Lm) != 0;
    #pragma unroll
    for (int l = 0; l < 2; ++l) {
      const float* rp = rotc + ((i*2 + l)*4)*8;
      rot_pairs<4>(amp, rp);          // ROT wire 3
      {                               // ROT wire 4+i (cross-lane)
        float2 u00 = make_float2(rp[8],  rp[9]),  u01 = make_float2(rp[10], rp[11]);
        float2 u10 = make_float2(rp[12], rp[13]), u11 = make_float2(rp[14], rp[15]);
        float2 cA, cB;
        cA.x = cb ? u11.x : u00.x; cA.y = cb ? u11.y : u00.y;
        cB.x = cb ? u10.x : u01.x; cB.y = cb ? u10.y : u01.y;
        #pragma unroll
        for (int s = 0; s < 8; ++s) {
          float2 o = shflx(amp[s], Lm);
          amp[s] = cadd(cmul(cA, amp[s]), cmul(cB, o));
        }
      }
      rot_pairs<2>(amp, rp + 16);     // ROT wire 7
      rot_pairs<1>(amp, rp + 24);     // ROT wire 8
      if (l == 0) {
        // CX(3 -> 4+i): slots with bit2=1 exchange across lanes
        #pragma unroll
        for (int s = 4; s < 8; ++s) amp[s] = shflx(amp[s], Lm);
        // CX(4+i -> 7): lanes with cb swap bit1 pairs
        cswap(cb, amp[0], amp[2]); cswap(cb, amp[1], amp[3]);
        cswap(cb, amp[4], amp[6]); cswap(cb, amp[5], amp[7]);
        // CX(7 -> 8): free register renames
        swap2(amp[2], amp[3]); swap2(amp[6], amp[7]);
        // CX(8 -> 3)
        swap2(amp[1], amp[5]); swap2(amp[3], amp[7]);
      } else {
        // CX(3 -> 7)
        swap2(amp[4], amp[6]); swap2(amp[5], amp[7]);
        // CX(4+i -> 8)
        cswap(cb, amp[0], amp[1]); cswap(cb, amp[2], amp[3]);
        cswap(cb, amp[4], amp[5]); cswap(cb, amp[6], amp[7]);
        // CX(7 -> 3)
        swap2(amp[2], amp[6]); swap2(amp[3], amp[7]);
        // CX(8 -> 4+i): slots with bit0=1 exchange across lanes
        amp[1] = shflx(amp[1], Lm); amp[3] = shflx(amp[3], Lm);
        amp[5] = shflx(amp[5], Lm); amp[7] = shflx(amp[7], Lm);
      }
    }
  }

  // ---- expz on wires 3 (bit2), 7 (bit1), 8 (bit0)
  float s3 = 0.f, s7 = 0.f, s8 = 0.f;
  #pragma unroll
  for (int s = 0; s < 8; ++s) {
    float p = amp[s].x*amp[s].x + amp[s].y*amp[s].y;
    s3 += (s & 4) ? -p : p;
    s7 += (s & 2) ? -p : p;
    s8 += (s & 1) ? -p : p;
  }
  #pragma unroll
  for (int o = 32; o; o >>= 1) {
    s3 += __shfl_xor(s3, o);
    s7 += __shfl_xor(s7, o);
    s8 += __shfl_xor(s8, o);
  }

  // ---- upd MLP + residual
  const int j1 = lane, j2 = lane + 64;
  float in5[5] = {ue0, ue1, s3, s7, s8};
  float h1 = bu1[j1], h2 = bu1[j2];
  #pragma unroll
  for (int k = 0; k < 5; ++k) {
    h1 = fmaf(in5[k], Wu1[k*128 + j1], h1);
    h2 = fmaf(in5[k], Wu1[k*128 + j2], h2);
  }
  h1 = LEAKY(h1); h2 = LEAKY(h2);
  float p0 = h1*Wu2[j1*2 + 0] + h2*Wu2[j2*2 + 0];
  float p1 = h1*Wu2[j1*2 + 1] + h2*Wu2[j2*2 + 1];
  #pragma unroll
  for (int o = 32; o; o >>= 1) { p0 += __shfl_xor(p0, o); p1 += __shfl_xor(p1, o); }
  float hh0 = ue0 + p0 + bu2[0];
  float hh1 = ue1 + p1 + bu2[1];

  // ---- layernorm over 2 elems
  float mu = 0.5f*(hh0 + hh1);
  float dd = hh0 - mu;
  float inv = rsqrtf(dd*dd + 1e-5f);
  float g0 = dd*inv*lng[0] + lnb[0];
  float g1 = -dd*inv*lng[1] + lnb[1];

  // ---- head 2->128->128->2 + sigmoid
  float a1f = LEAKY(g0*Wf1[j1] + g1*Wf1[128 + j1] + bf1[j1]);
  float a2f = LEAKY(g0*Wf1[j2] + g1*Wf1[128 + j2] + bf1[j2]);
  act[j1] = a1f; act[j2] = a2f;
  __syncthreads();
  float c1 = bf2[j1], c2 = bf2[j2];
  for (int k = 0; k < 128; ++k) {
    float ak = act[k];
    c1 = fmaf(ak, Wf2[k*128 + j1], c1);
    c2 = fmaf(ak, Wf2[k*128 + j2], c2);
  }
  c1 = LEAKY(c1); c2 = LEAKY(c2);
  float o0 = c1*Wf3[j1*2 + 0] + c2*Wf3[j2*2 + 0];
  float o1 = c1*Wf3[j1*2 + 1] + c2*Wf3[j2*2 + 1];
  #pragma unroll
  for (int o = 32; o; o >>= 1) { o0 += __shfl_xor(o0, o); o1 += __shfl_xor(o1, o); }
  if (lane == 0) {
    out[u*2 + 0] = 1.f/(1.f + expf(-(o0 + bf3[0])));
    out[u*2 + 1] = 1.f/(1.f + expf(-(o1 + bf3[1])));
  }
}

extern "C" void kernel_launch(void* const* d_in, const int* in_sizes, int n_in,
                              void* d_out, int out_size, void* d_ws, size_t ws_size,
                              hipStream_t stream) {
  (void)in_sizes; (void)n_in; (void)out_size; (void)ws_size;
  const float* x_ue      = (const float*)d_in[0];
  const float* x_ap      = (const float*)d_in[1];
  const float* edge_attr = (const float*)d_in[2];
  const int*   edge_src  = (const int*)d_in[3];
  const float* Wn1u = (const float*)d_in[5];
  const float* bn1u = (const float*)d_in[6];
  const float* Wn2u = (const float*)d_in[7];
  const float* bn2u = (const float*)d_in[8];
  const float* Wn1a = (const float*)d_in[9];
  const float* bn1a = (const float*)d_in[10];
  const float* Wn2a = (const float*)d_in[11];
  const float* bn2a = (const float*)d_in[12];
  const float* We1  = (const float*)d_in[13];
  const float* be1  = (const float*)d_in[14];
  const float* We2  = (const float*)d_in[15];
  const float* be2  = (const float*)d_in[16];
  const float* strong = (const float*)d_in[17];
  const float* inits  = (const float*)d_in[18];
  const float* update = (const float*)d_in[19];
  const float* Wu1  = (const float*)d_in[20];
  const float* bu1  = (const float*)d_in[21];
  const float* Wu2  = (const float*)d_in[22];
  const float* bu2  = (const float*)d_in[23];
  const float* ln_g = (const float*)d_in[24];
  const float* ln_b = (const float*)d_in[25];
  const float* Wf1  = (const float*)d_in[26];
  const float* bf1  = (const float*)d_in[27];
  const float* Wf2  = (const float*)d_in[28];
  const float* bf2  = (const float*)d_in[29];
  const float* Wf3  = (const float*)d_in[30];
  const float* bf3  = (const float*)d_in[31];

  float* ws = (float*)d_ws;

  prep_kernel<<<137, 256, 0, stream>>>(x_ue, x_ap, edge_attr,
                                       Wn1u, bn1u, Wn2u, bn2u,
                                       Wn1a, bn1a, Wn2a, bn2a,
                                       We1, be1, We2, be2,
                                       strong, inits, update, ws);
  circuit_kernel<<<4096, 128, 0, stream>>>(ws, edge_src,
                                           Wu1, bu1, Wu2, bu2, ln_g, ln_b,
                                           Wf1, bf1, Wf2, bf2, Wf3, bf3,
                                           (float*)d_out);
}